// Round 10
// baseline (72.723 us; speedup 1.0000x reference)
//
#include <hip/hip_runtime.h>
#include <hip/hip_fp16.h>

#define N_NODES 50000
#define N_EDGES 800000
#define D_IN 64
#define MAXD 64
#define BSHIFT 7                       // 128 nodes per bucket
#define BNODES 128
#define NBUCKET 391                    // ceil(50000/128)
#define NSCB 128                       // hist/scatter blocks
#define EPB (N_EDGES / NSCB)           // 6250 edges per block
#define NENT (NBUCKET * NSCB)          // 50048 (bucket-major)
#define SCB ((NENT + 255) / 256)       // 196 scan blocks

typedef _Float16 f16x8 __attribute__((ext_vector_type(8)));
typedef float f32x4 __attribute__((ext_vector_type(4)));

union H8 { uint4 v; unsigned int u[4]; f16x8 h; };

__device__ __forceinline__ f32x4 MM(const H8& a, const H8& b, f32x4 c) {
    return __builtin_amdgcn_mfma_f32_16x16x32_f16(a.h, b.h, c, 0, 0, 0);
}
__device__ __forceinline__ unsigned int pkh(float a, float b) {
    __half2 h = __floats2half2_rn(a, b);
    unsigned int u;
    __builtin_memcpy(&u, &h, 4);
    return u;
}

// ---- K0 (MFMA): xw1n = x@w1n ; xr1b = x@w1r + b1 (fp16 out) ----
// wave = 16 nodes. D[out][node] = W^T A-op (LDS f16) x^T B-op (global f32->f16).
__global__ __launch_bounds__(256) void k_lin1(
        const float* __restrict__ x,
        const float* __restrict__ w1n, const float* __restrict__ w1r,
        const float* __restrict__ b1,
        __half* __restrict__ xw1n, __half* __restrict__ xr1b) {
    __shared__ __align__(16) __half s_w1t[32 * 72];   // [out 32][k 64 pad 72]
    const int tid = threadIdx.x;
    for (int i = tid; i < 2048; i += 256) {
        int o = i & 31, k = i >> 5;
        float v = (o < 16) ? w1n[k * 16 + o] : w1r[k * 16 + (o - 16)];
        s_w1t[o * 72 + k] = __float2half(v);
    }
    __syncthreads();
    const int l = tid & 63, li = l & 15, g = l >> 4;
    const int wid = tid >> 6;
    const int node = blockIdx.x * 64 + wid * 16 + li;
    const int nodec = node < N_NODES ? node : N_NODES - 1;

    // B frags: x[node][k], k = 8g..+8 (s=0) and 32+8g..+8 (s=1)
    H8 B0, B1;
    {
        const float4* xp = (const float4*)(x + nodec * 64 + 8 * g);
        float4 v0 = xp[0], v1 = xp[1];
        B0.u[0] = pkh(v0.x, v0.y); B0.u[1] = pkh(v0.z, v0.w);
        B0.u[2] = pkh(v1.x, v1.y); B0.u[3] = pkh(v1.z, v1.w);
        const float4* xq = (const float4*)(x + nodec * 64 + 32 + 8 * g);
        float4 w0 = xq[0], w1 = xq[1];
        B1.u[0] = pkh(w0.x, w0.y); B1.u[1] = pkh(w0.z, w0.w);
        B1.u[2] = pkh(w1.x, w1.y); B1.u[3] = pkh(w1.z, w1.w);
    }
    H8 A;
    f32x4 c0 = {0.f, 0.f, 0.f, 0.f};                       // t=0 -> xw1n
    A.v = *(const uint4*)(s_w1t + li * 72 + 8 * g);
    c0 = MM(A, B0, c0);
    A.v = *(const uint4*)(s_w1t + li * 72 + 32 + 8 * g);
    c0 = MM(A, B1, c0);
    f32x4 c1 = *(const f32x4*)(b1 + 4 * g);                // t=1 -> xr1b (+b1)
    A.v = *(const uint4*)(s_w1t + (16 + li) * 72 + 8 * g);
    c1 = MM(A, B0, c1);
    A.v = *(const uint4*)(s_w1t + (16 + li) * 72 + 32 + 8 * g);
    c1 = MM(A, B1, c1);

    if (node < N_NODES) {
        uint2 s0, s1;
        s0.x = pkh(c0[0], c0[1]); s0.y = pkh(c0[2], c0[3]);
        s1.x = pkh(c1[0], c1[1]); s1.y = pkh(c1[2], c1[3]);
        *(uint2*)(xw1n + node * 16 + 4 * g) = s0;          // feats 4g..4g+3
        *(uint2*)(xr1b + node * 16 + 4 * g) = s1;
    }
}

// ---- K1: per-block bucket histogram (bucket-major output) ----
__global__ __launch_bounds__(256) void k_hist(const int* __restrict__ dst,
                                              int* __restrict__ ghist) {
    __shared__ int lh[NBUCKET];
    for (int i = threadIdx.x; i < NBUCKET; i += 256) lh[i] = 0;
    __syncthreads();
    const int base = blockIdx.x * EPB;
    for (int i = threadIdx.x; i < EPB; i += 256)
        atomicAdd(&lh[dst[base + i] >> BSHIFT], 1);
    __syncthreads();
    for (int i = threadIdx.x; i < NBUCKET; i += 256)
        ghist[i * NSCB + blockIdx.x] = lh[i];
}

// ---- K2a: per-block exclusive scan + block sums ----
__global__ __launch_bounds__(256) void k_scanA(const int* __restrict__ ghist,
                                               int* __restrict__ part,
                                               int* __restrict__ blockSums) {
    __shared__ int s[256];
    const int i = blockIdx.x * 256 + threadIdx.x;
    int v = (i < NENT) ? ghist[i] : 0;
    s[threadIdx.x] = v;
    __syncthreads();
    for (int d = 1; d < 256; d <<= 1) {
        int t = (threadIdx.x >= d) ? s[threadIdx.x - d] : 0;
        __syncthreads();
        s[threadIdx.x] += t;
        __syncthreads();
    }
    if (i < NENT) part[i] = s[threadIdx.x] - v;
    if (threadIdx.x == 255) blockSums[blockIdx.x] = s[255];
}

// ---- K2b: scan of SCB block sums ----
__global__ __launch_bounds__(256) void k_scanB(int* __restrict__ blockSums) {
    __shared__ int s[256];
    const int t = threadIdx.x;
    int v = (t < SCB) ? blockSums[t] : 0;
    s[t] = v;
    __syncthreads();
    for (int d = 1; d < 256; d <<= 1) {
        int u = (t >= d) ? s[t - d] : 0;
        __syncthreads();
        s[t] += u;
        __syncthreads();
    }
    if (t < SCB) blockSums[t] = s[t] - v;
}

// ---- K2c: add-back + bucketStart extraction ----
__global__ __launch_bounds__(256) void k_scanC(const int* __restrict__ part,
                                               const int* __restrict__ blockSums,
                                               int* __restrict__ gscan,
                                               int* __restrict__ bucketStart) {
    const int i = blockIdx.x * 256 + threadIdx.x;
    if (i < NENT) {
        int o = part[i] + blockSums[blockIdx.x];
        gscan[i] = o;
        if ((i & (NSCB - 1)) == 0) bucketStart[i >> BSHIFT] = o;
    }
    if (i == 0) bucketStart[NBUCKET] = N_EDGES;
}

// ---- K3: scatter edges into bucket-grouped staging (packed u32) ----
__global__ __launch_bounds__(256) void k_scatter(const int* __restrict__ src,
                                                 const int* __restrict__ dst,
                                                 const int* __restrict__ gscan,
                                                 unsigned int* __restrict__ staging) {
    __shared__ int cur[NBUCKET];
    for (int i = threadIdx.x; i < NBUCKET; i += 256)
        cur[i] = gscan[i * NSCB + blockIdx.x];
    __syncthreads();
    const int base = blockIdx.x * EPB;
    for (int i = threadIdx.x; i < EPB; i += 256) {
        int d = dst[base + i], s = src[base + i];
        int pos = atomicAdd(&cur[d >> BSHIFT], 1);
        staging[pos] = ((unsigned int)(d & (BNODES - 1)) << 16) | (unsigned int)s;
    }
}

// ---- K4: per-bucket padded-table build in LDS, coalesced write-out ----
__global__ __launch_bounds__(256) void k_build(const unsigned int* __restrict__ staging,
                                               const int* __restrict__ bucketStart,
                                               unsigned int* __restrict__ nbrU,
                                               int* __restrict__ deg) {
    __shared__ unsigned short ltbl[BNODES * MAXD];
    __shared__ int lcnt[BNODES];
    const int tid = threadIdx.x, b = blockIdx.x;
    if (tid < BNODES) lcnt[tid] = 0;
    __syncthreads();
    const int beg = bucketStart[b], end = bucketStart[b + 1];
    for (int i = beg + tid; i < end; i += 256) {
        unsigned int u = staging[i];
        int dl = u >> 16, s = u & 0xFFFF;
        int slot = atomicAdd(&lcnt[dl], 1);
        if (slot < MAXD) ltbl[(dl << 6) + slot] = (unsigned short)s;
    }
    __syncthreads();
    const int nbase = b << BSHIFT;
    for (int i = tid; i < BNODES * 32; i += 256) {
        int nl = i >> 5, j = i & 31;
        int node = nbase + nl;
        if (node < N_NODES && 2 * j < lcnt[nl]) {
            unsigned int lo = ltbl[(nl << 6) + 2 * j];
            unsigned int hi = ltbl[(nl << 6) + 2 * j + 1];
            nbrU[(node << 5) + j] = lo | (hi << 16);
        }
    }
    if (tid < BNODES && nbase + tid < N_NODES) deg[nbase + tid] = lcnt[tid];
}

// ---- K5: h1 = relu(mean_nbrs(xw1n) + xr1b)  (half2 lanes: 8 thr/node) ----
__global__ __launch_bounds__(256) void k_agg1(
        const __half* __restrict__ xw1n, const __half* __restrict__ xr1b,
        const int* __restrict__ deg, const unsigned short* __restrict__ nbr,
        __half* __restrict__ h1) {
    const int t = blockIdx.x * 256 + threadIdx.x;
    if (t >= N_NODES * 8) return;
    const int node = t >> 3, fp = t & 7;
    int c = deg[node];
    float inv = c > 0 ? 1.f / (float)c : 1.f;
    int cc = c > MAXD ? MAXD : c;
    const unsigned short* np = nbr + (node << 6);
    float2 a0 = {0.f, 0.f}, a1 = {0.f, 0.f}, a2 = {0.f, 0.f}, a3 = {0.f, 0.f};
    int j = 0;
    for (; j + 4 <= cc; j += 4) {
        float2 v0 = __half22float2(*(const __half2*)(xw1n + (np[j + 0] << 4) + (fp << 1)));
        float2 v1 = __half22float2(*(const __half2*)(xw1n + (np[j + 1] << 4) + (fp << 1)));
        float2 v2 = __half22float2(*(const __half2*)(xw1n + (np[j + 2] << 4) + (fp << 1)));
        float2 v3 = __half22float2(*(const __half2*)(xw1n + (np[j + 3] << 4) + (fp << 1)));
        a0.x += v0.x; a0.y += v0.y; a1.x += v1.x; a1.y += v1.y;
        a2.x += v2.x; a2.y += v2.y; a3.x += v3.x; a3.y += v3.y;
    }
    for (; j < cc; ++j) {
        float2 v = __half22float2(*(const __half2*)(xw1n + (np[j] << 4) + (fp << 1)));
        a0.x += v.x; a0.y += v.y;
    }
    float2 r = __half22float2(*(const __half2*)(xr1b + (node << 4) + (fp << 1)));
    float rx = fmaxf((a0.x + a1.x + a2.x + a3.x) * inv + r.x, 0.f);
    float ry = fmaxf((a0.y + a1.y + a2.y + a3.y) * inv + r.y, 0.f);
    *(__half2*)(h1 + (node << 4) + (fp << 1)) = __floats2half2_rn(rx, ry);
}

// ---- K6: agg2 = mean_nbrs(h1)  (half2 lanes) ----
__global__ __launch_bounds__(256) void k_agg2(
        const __half* __restrict__ h1,
        const int* __restrict__ deg, const unsigned short* __restrict__ nbr,
        __half* __restrict__ agg2) {
    const int t = blockIdx.x * 256 + threadIdx.x;
    if (t >= N_NODES * 8) return;
    const int node = t >> 3, fp = t & 7;
    int c = deg[node];
    float inv = c > 0 ? 1.f / (float)c : 1.f;
    int cc = c > MAXD ? MAXD : c;
    const unsigned short* np = nbr + (node << 6);
    float2 a0 = {0.f, 0.f}, a1 = {0.f, 0.f}, a2 = {0.f, 0.f}, a3 = {0.f, 0.f};
    int j = 0;
    for (; j + 4 <= cc; j += 4) {
        float2 v0 = __half22float2(*(const __half2*)(h1 + (np[j + 0] << 4) + (fp << 1)));
        float2 v1 = __half22float2(*(const __half2*)(h1 + (np[j + 1] << 4) + (fp << 1)));
        float2 v2 = __half22float2(*(const __half2*)(h1 + (np[j + 2] << 4) + (fp << 1)));
        float2 v3 = __half22float2(*(const __half2*)(h1 + (np[j + 3] << 4) + (fp << 1)));
        a0.x += v0.x; a0.y += v0.y; a1.x += v1.x; a1.y += v1.y;
        a2.x += v2.x; a2.y += v2.y; a3.x += v3.x; a3.y += v3.y;
    }
    for (; j < cc; ++j) {
        float2 v = __half22float2(*(const __half2*)(h1 + (np[j] << 4) + (fp << 1)));
        a0.x += v.x; a0.y += v.y;
    }
    *(__half2*)(agg2 + (node << 4) + (fp << 1)) =
        __floats2half2_rn((a0.x + a1.x + a2.x + a3.x) * inv,
                          (a0.y + a1.y + a2.y + a3.y) * inv);
}

// ---- K7 (k_head, MFMA): SAGE2 + MLP head, transposed D[out][node] ----
// wave = 16 nodes. Weights = A-op (transposed f16 LDS). Activations = B-op.
// C/D: col = lane&15 = node, row = (lane>>4)*4 + r = out-feat.
// B-frag: col = lane&15 = node, k = (lane>>4)*8 + e  -> same node per lane,
// so layer handoff is 8 shfl + cvt_pkrtz per frag (no LDS transpose).
__global__ __launch_bounds__(256) void k_head(
        const __half* __restrict__ h1, const __half* __restrict__ agg2,
        const float* __restrict__ w2n, const float* __restrict__ w2r,
        const float* __restrict__ b2,
        const float* __restrict__ fw1, const float* __restrict__ fb1,
        const float* __restrict__ fw2, const float* __restrict__ fb2,
        const float* __restrict__ fw3, const float* __restrict__ fb3,
        float* __restrict__ out) {
    __shared__ __align__(16) __half s_w2t[32 * 40];     // [out 32][k 32 pad 40]
    __shared__ __align__(16) __half s_fw1t[64 * 40];    // [out 64][k 32 pad 40]
    __shared__ __align__(16) __half s_fw2t[128 * 72];   // [out 128][k 64 pad 72]

    const int tid = threadIdx.x;
    for (int i = tid; i < 1024; i += 256) {
        int o = i & 31, k = i >> 5;
        float v = (k < 16) ? w2n[k * 32 + o] : w2r[(k - 16) * 32 + o];
        s_w2t[o * 40 + k] = __float2half(v);
    }
    for (int i = tid; i < 2048; i += 256) {
        int o = i & 63, k = i >> 6;
        s_fw1t[o * 40 + k] = __float2half(fw1[k * 64 + o]);
    }
    for (int i = tid; i < 8192; i += 256) {
        int o = i & 127, k = i >> 7;
        s_fw2t[o * 72 + k] = __float2half(fw2[k * 128 + o]);
    }
    __syncthreads();

    const int l = tid & 63, li = l & 15, g = l >> 4;
    const int wid = tid >> 6;
    const int node = blockIdx.x * 64 + wid * 16 + li;
    const int nodec = node < N_NODES ? node : N_NODES - 1;
    const int sl0 = li + 32 * (g & 1), sl1 = sl0 + 16;   // shfl sources
    const int tsel = g >> 1;

    // z B-frag: k<16 = agg2[node][0..15], k>=16 = h1[node][0..15] (fp16 direct)
    H8 Bz;
    {
        const __half* zb = (g < 2) ? agg2 : h1;
        Bz.v = *(const uint4*)(zb + (nodec << 4) + ((g & 1) << 3));
    }

    // ---- h2 = relu(z @ W2cat + b2): 2 M-tiles, K=32 ----
    unsigned int p01[2], p23[2];
#pragma unroll
    for (int t = 0; t < 2; ++t) {
        f32x4 c = *(const f32x4*)(b2 + 16 * t + 4 * g);
        H8 A; A.v = *(const uint4*)(s_w2t + (16 * t + li) * 40 + 8 * g);
        c = MM(A, Bz, c);
        p01[t] = pkh(fmaxf(c[0], 0.f), fmaxf(c[1], 0.f));
        p23[t] = pkh(fmaxf(c[2], 0.f), fmaxf(c[3], 0.f));
    }
    H8 Bh2;
    {
        unsigned int a, b;
        a = __shfl((int)p01[0], sl0); b = __shfl((int)p01[1], sl0); Bh2.u[0] = tsel ? b : a;
        a = __shfl((int)p23[0], sl0); b = __shfl((int)p23[1], sl0); Bh2.u[1] = tsel ? b : a;
        a = __shfl((int)p01[0], sl1); b = __shfl((int)p01[1], sl1); Bh2.u[2] = tsel ? b : a;
        a = __shfl((int)p23[0], sl1); b = __shfl((int)p23[1], sl1); Bh2.u[3] = tsel ? b : a;
    }

    // ---- h3 = relu(h2 @ fw1 + fb1): 4 M-tiles, K=32 ----
    unsigned int q01[4], q23[4];
#pragma unroll
    for (int t = 0; t < 4; ++t) {
        f32x4 c = *(const f32x4*)(fb1 + 16 * t + 4 * g);
        H8 A; A.v = *(const uint4*)(s_fw1t + (16 * t + li) * 40 + 8 * g);
        c = MM(A, Bh2, c);
        q01[t] = pkh(fmaxf(c[0], 0.f), fmaxf(c[1], 0.f));
        q23[t] = pkh(fmaxf(c[2], 0.f), fmaxf(c[3], 0.f));
    }
    H8 Bh3[2];
#pragma unroll
    for (int s = 0; s < 2; ++s) {
        unsigned int a, b;
        a = __shfl((int)q01[2 * s], sl0); b = __shfl((int)q01[2 * s + 1], sl0); Bh3[s].u[0] = tsel ? b : a;
        a = __shfl((int)q23[2 * s], sl0); b = __shfl((int)q23[2 * s + 1], sl0); Bh3[s].u[1] = tsel ? b : a;
        a = __shfl((int)q01[2 * s], sl1); b = __shfl((int)q01[2 * s + 1], sl1); Bh3[s].u[2] = tsel ? b : a;
        a = __shfl((int)q23[2 * s], sl1); b = __shfl((int)q23[2 * s + 1], sl1); Bh3[s].u[3] = tsel ? b : a;
    }

    // ---- h4 = relu(h3 @ fw2 + fb2); out = h4 @ fw3: 8 M-tiles, K=64 ----
    float o0 = 0.f, o1 = 0.f;
#pragma unroll
    for (int m = 0; m < 8; ++m) {
        f32x4 c = *(const f32x4*)(fb2 + 16 * m + 4 * g);
        H8 A;
        A.v = *(const uint4*)(s_fw2t + (16 * m + li) * 72 + 8 * g);
        c = MM(A, Bh3[0], c);
        A.v = *(const uint4*)(s_fw2t + (16 * m + li) * 72 + 32 + 8 * g);
        c = MM(A, Bh3[1], c);
        const float4* wp = (const float4*)(fw3 + (16 * m + 4 * g) * 2);
        float4 wA = wp[0], wB = wp[1];
        float r0 = fmaxf(c[0], 0.f), r1 = fmaxf(c[1], 0.f);
        float r2 = fmaxf(c[2], 0.f), r3 = fmaxf(c[3], 0.f);
        o0 += r0 * wA.x + r1 * wA.z + r2 * wB.x + r3 * wB.z;
        o1 += r0 * wA.y + r1 * wA.w + r2 * wB.y + r3 * wB.w;
    }
    o0 += __shfl_xor(o0, 16); o0 += __shfl_xor(o0, 32);
    o1 += __shfl_xor(o1, 16); o1 += __shfl_xor(o1, 32);
    if (g == 0 && node < N_NODES) {
        float2 r; r.x = o0 + fb3[0]; r.y = o1 + fb3[1];
        *(float2*)(out + node * 2) = r;
    }
}

extern "C" void kernel_launch(void* const* d_in, const int* in_sizes, int n_in,
                              void* d_out, int out_size, void* d_ws, size_t ws_size,
                              hipStream_t stream) {
    const float* x   = (const float*)d_in[0];
    const int*   ei  = (const int*)d_in[1];
    const int*   src = ei;
    const int*   dst = ei + N_EDGES;
    const float* w1n = (const float*)d_in[2];
    const float* w1r = (const float*)d_in[3];
    const float* b1  = (const float*)d_in[4];
    const float* w2n = (const float*)d_in[5];
    const float* w2r = (const float*)d_in[6];
    const float* b2  = (const float*)d_in[7];
    const float* fw1 = (const float*)d_in[8];
    const float* fb1 = (const float*)d_in[9];
    const float* fw2 = (const float*)d_in[10];
    const float* fb2 = (const float*)d_in[11];
    const float* fw3 = (const float*)d_in[12];
    const float* fb3 = (const float*)d_in[13];
    float* out = (float*)d_out;

    // workspace layout (~18.6 MB)
    unsigned int*   nbrU        = (unsigned int*)d_ws;              // 50000*32 uints (6.4MB)
    int*            deg         = (int*)(nbrU + N_NODES * 32);      // 50000
    __half*         xw1n        = (__half*)(deg + N_NODES);         // 800000
    __half*         xr1b        = xw1n + N_EDGES;                   // 800000
    __half*         h1          = xr1b + N_EDGES;                   // 800000
    __half*         agg2        = h1 + N_EDGES;                     // 800000
    unsigned int*   staging     = (unsigned int*)(agg2 + N_EDGES);  // 800000 (3.2MB)
    int*            ghist       = (int*)(staging + N_EDGES);        // 50048
    int*            gscan       = ghist + NENT;                     // 50048
    int*            part        = gscan + NENT;                     // 50048
    int*            blockSums   = part + NENT;                      // 196
    int*            bucketStart = blockSums + SCB;                  // 392

    const unsigned short* nbr = (const unsigned short*)nbrU;

    k_lin1<<<(N_NODES + 63) / 64, 256, 0, stream>>>(x, w1n, w1r, b1, xw1n, xr1b);
    k_hist<<<NSCB, 256, 0, stream>>>(dst, ghist);
    k_scanA<<<SCB, 256, 0, stream>>>(ghist, part, blockSums);
    k_scanB<<<1, 256, 0, stream>>>(blockSums);
    k_scanC<<<SCB, 256, 0, stream>>>(part, blockSums, gscan, bucketStart);
    k_scatter<<<NSCB, 256, 0, stream>>>(src, dst, gscan, staging);
    k_build<<<NBUCKET, 256, 0, stream>>>(staging, bucketStart, nbrU, deg);
    k_agg1<<<(N_NODES * 8 + 255) / 256, 256, 0, stream>>>(xw1n, xr1b, deg, nbr, h1);
    k_agg2<<<(N_NODES * 8 + 255) / 256, 256, 0, stream>>>(h1, deg, nbr, agg2);
    k_head<<<(N_NODES + 63) / 64, 256, 0, stream>>>(h1, agg2, w2n, w2r, b2,
                                                    fw1, fb1, fw2, fb2, fw3, fb3, out);
}

// Round 11
// 72.675 us; speedup vs baseline: 1.0007x; 1.0007x over previous
//
#include <hip/hip_runtime.h>
#include <hip/hip_fp16.h>

#define N_NODES 50000
#define N_EDGES 800000
#define D_IN 64
#define MAXD 64
#define BSHIFT 7                       // 128 nodes per bucket
#define BNODES 128
#define NBUCKET 391                    // ceil(50000/128)
#define NSCB 128                       // hist/scatter blocks
#define EPB (N_EDGES / NSCB)           // 6250 edges per block
#define NENT (NBUCKET * NSCB)          // 50048 (bucket-major)
#define SCB ((NENT + 255) / 256)       // 196 scan blocks

typedef _Float16 f16x8 __attribute__((ext_vector_type(8)));
typedef float f32x4 __attribute__((ext_vector_type(4)));

union H8 { uint4 v; unsigned int u[4]; f16x8 h; };

__device__ __forceinline__ f32x4 MM(const H8& a, const H8& b, f32x4 c) {
    return __builtin_amdgcn_mfma_f32_16x16x32_f16(a.h, b.h, c, 0, 0, 0);
}
__device__ __forceinline__ unsigned int pkh(float a, float b) {
    __half2 h = __floats2half2_rn(a, b);
    unsigned int u;
    __builtin_memcpy(&u, &h, 4);
    return u;
}

// ---- K0 (MFMA): xw1n = x@w1n ; xr1b = x@w1r + b1 (fp16 out) ----
// wave = 16 nodes. D[out][node] = W^T A-op (LDS f16) x^T B-op (global f32->f16).
__global__ __launch_bounds__(256) void k_lin1(
        const float* __restrict__ x,
        const float* __restrict__ w1n, const float* __restrict__ w1r,
        const float* __restrict__ b1,
        __half* __restrict__ xw1n, __half* __restrict__ xr1b) {
    __shared__ __align__(16) __half s_w1t[32 * 72];   // [out 32][k 64 pad 72]
    const int tid = threadIdx.x;
    for (int i = tid; i < 2048; i += 256) {
        int o = i & 31, k = i >> 5;
        float v = (o < 16) ? w1n[k * 16 + o] : w1r[k * 16 + (o - 16)];
        s_w1t[o * 72 + k] = __float2half(v);
    }
    __syncthreads();
    const int l = tid & 63, li = l & 15, g = l >> 4;
    const int wid = tid >> 6;
    const int node = blockIdx.x * 64 + wid * 16 + li;
    const int nodec = node < N_NODES ? node : N_NODES - 1;

    // B frags: x[node][k], k = 8g..+8 (s=0) and 32+8g..+8 (s=1)
    H8 B0, B1;
    {
        const float4* xp = (const float4*)(x + nodec * 64 + 8 * g);
        float4 v0 = xp[0], v1 = xp[1];
        B0.u[0] = pkh(v0.x, v0.y); B0.u[1] = pkh(v0.z, v0.w);
        B0.u[2] = pkh(v1.x, v1.y); B0.u[3] = pkh(v1.z, v1.w);
        const float4* xq = (const float4*)(x + nodec * 64 + 32 + 8 * g);
        float4 w0 = xq[0], w1 = xq[1];
        B1.u[0] = pkh(w0.x, w0.y); B1.u[1] = pkh(w0.z, w0.w);
        B1.u[2] = pkh(w1.x, w1.y); B1.u[3] = pkh(w1.z, w1.w);
    }
    H8 A;
    f32x4 c0 = {0.f, 0.f, 0.f, 0.f};                       // t=0 -> xw1n
    A.v = *(const uint4*)(s_w1t + li * 72 + 8 * g);
    c0 = MM(A, B0, c0);
    A.v = *(const uint4*)(s_w1t + li * 72 + 32 + 8 * g);
    c0 = MM(A, B1, c0);
    f32x4 c1 = *(const f32x4*)(b1 + 4 * g);                // t=1 -> xr1b (+b1)
    A.v = *(const uint4*)(s_w1t + (16 + li) * 72 + 8 * g);
    c1 = MM(A, B0, c1);
    A.v = *(const uint4*)(s_w1t + (16 + li) * 72 + 32 + 8 * g);
    c1 = MM(A, B1, c1);

    if (node < N_NODES) {
        uint2 s0, s1;
        s0.x = pkh(c0[0], c0[1]); s0.y = pkh(c0[2], c0[3]);
        s1.x = pkh(c1[0], c1[1]); s1.y = pkh(c1[2], c1[3]);
        *(uint2*)(xw1n + node * 16 + 4 * g) = s0;          // feats 4g..4g+3
        *(uint2*)(xr1b + node * 16 + 4 * g) = s1;
    }
}

// ---- K1: per-block bucket histogram (bucket-major output) ----
__global__ __launch_bounds__(256) void k_hist(const int* __restrict__ dst,
                                              int* __restrict__ ghist) {
    __shared__ int lh[NBUCKET];
    for (int i = threadIdx.x; i < NBUCKET; i += 256) lh[i] = 0;
    __syncthreads();
    const int base = blockIdx.x * EPB;
    for (int i = threadIdx.x; i < EPB; i += 256)
        atomicAdd(&lh[dst[base + i] >> BSHIFT], 1);
    __syncthreads();
    for (int i = threadIdx.x; i < NBUCKET; i += 256)
        ghist[i * NSCB + blockIdx.x] = lh[i];
}

// ---- K2a: per-block exclusive scan + block sums ----
__global__ __launch_bounds__(256) void k_scanA(const int* __restrict__ ghist,
                                               int* __restrict__ part,
                                               int* __restrict__ blockSums) {
    __shared__ int s[256];
    const int i = blockIdx.x * 256 + threadIdx.x;
    int v = (i < NENT) ? ghist[i] : 0;
    s[threadIdx.x] = v;
    __syncthreads();
    for (int d = 1; d < 256; d <<= 1) {
        int t = (threadIdx.x >= d) ? s[threadIdx.x - d] : 0;
        __syncthreads();
        s[threadIdx.x] += t;
        __syncthreads();
    }
    if (i < NENT) part[i] = s[threadIdx.x] - v;
    if (threadIdx.x == 255) blockSums[blockIdx.x] = s[255];
}

// ---- K2b: scan of SCB block sums ----
__global__ __launch_bounds__(256) void k_scanB(int* __restrict__ blockSums) {
    __shared__ int s[256];
    const int t = threadIdx.x;
    int v = (t < SCB) ? blockSums[t] : 0;
    s[t] = v;
    __syncthreads();
    for (int d = 1; d < 256; d <<= 1) {
        int u = (t >= d) ? s[t - d] : 0;
        __syncthreads();
        s[t] += u;
        __syncthreads();
    }
    if (t < SCB) blockSums[t] = s[t] - v;
}

// ---- K2c: add-back + bucketStart extraction ----
__global__ __launch_bounds__(256) void k_scanC(const int* __restrict__ part,
                                               const int* __restrict__ blockSums,
                                               int* __restrict__ gscan,
                                               int* __restrict__ bucketStart) {
    const int i = blockIdx.x * 256 + threadIdx.x;
    if (i < NENT) {
        int o = part[i] + blockSums[blockIdx.x];
        gscan[i] = o;
        if ((i & (NSCB - 1)) == 0) bucketStart[i >> BSHIFT] = o;
    }
    if (i == 0) bucketStart[NBUCKET] = N_EDGES;
}

// ---- K3: scatter edges into bucket-grouped staging (packed u32) ----
__global__ __launch_bounds__(256) void k_scatter(const int* __restrict__ src,
                                                 const int* __restrict__ dst,
                                                 const int* __restrict__ gscan,
                                                 unsigned int* __restrict__ staging) {
    __shared__ int cur[NBUCKET];
    for (int i = threadIdx.x; i < NBUCKET; i += 256)
        cur[i] = gscan[i * NSCB + blockIdx.x];
    __syncthreads();
    const int base = blockIdx.x * EPB;
    for (int i = threadIdx.x; i < EPB; i += 256) {
        int d = dst[base + i], s = src[base + i];
        int pos = atomicAdd(&cur[d >> BSHIFT], 1);
        staging[pos] = ((unsigned int)(d & (BNODES - 1)) << 16) | (unsigned int)s;
    }
}

// ---- K4: per-bucket padded-table build in LDS, coalesced write-out ----
__global__ __launch_bounds__(256) void k_build(const unsigned int* __restrict__ staging,
                                               const int* __restrict__ bucketStart,
                                               unsigned int* __restrict__ nbrU,
                                               int* __restrict__ deg) {
    __shared__ unsigned short ltbl[BNODES * MAXD];
    __shared__ int lcnt[BNODES];
    const int tid = threadIdx.x, b = blockIdx.x;
    if (tid < BNODES) lcnt[tid] = 0;
    __syncthreads();
    const int beg = bucketStart[b], end = bucketStart[b + 1];
    for (int i = beg + tid; i < end; i += 256) {
        unsigned int u = staging[i];
        int dl = u >> 16, s = u & 0xFFFF;
        int slot = atomicAdd(&lcnt[dl], 1);
        if (slot < MAXD) ltbl[(dl << 6) + slot] = (unsigned short)s;
    }
    __syncthreads();
    const int nbase = b << BSHIFT;
    for (int i = tid; i < BNODES * 32; i += 256) {
        int nl = i >> 5, j = i & 31;
        int node = nbase + nl;
        if (node < N_NODES && 2 * j < lcnt[nl]) {
            unsigned int lo = ltbl[(nl << 6) + 2 * j];
            unsigned int hi = ltbl[(nl << 6) + 2 * j + 1];
            nbrU[(node << 5) + j] = lo | (hi << 16);
        }
    }
    if (tid < BNODES && nbase + tid < N_NODES) deg[nbase + tid] = lcnt[tid];
}

// ---- K5: h1 = relu(mean_nbrs(xw1n) + xr1b)  (half2 lanes: 8 thr/node) ----
__global__ __launch_bounds__(256) void k_agg1(
        const __half* __restrict__ xw1n, const __half* __restrict__ xr1b,
        const int* __restrict__ deg, const unsigned short* __restrict__ nbr,
        __half* __restrict__ h1) {
    const int t = blockIdx.x * 256 + threadIdx.x;
    if (t >= N_NODES * 8) return;
    const int node = t >> 3, fp = t & 7;
    int c = deg[node];
    float inv = c > 0 ? 1.f / (float)c : 1.f;
    int cc = c > MAXD ? MAXD : c;
    const unsigned short* np = nbr + (node << 6);
    float2 a0 = {0.f, 0.f}, a1 = {0.f, 0.f}, a2 = {0.f, 0.f}, a3 = {0.f, 0.f};
    int j = 0;
    for (; j + 4 <= cc; j += 4) {
        float2 v0 = __half22float2(*(const __half2*)(xw1n + (np[j + 0] << 4) + (fp << 1)));
        float2 v1 = __half22float2(*(const __half2*)(xw1n + (np[j + 1] << 4) + (fp << 1)));
        float2 v2 = __half22float2(*(const __half2*)(xw1n + (np[j + 2] << 4) + (fp << 1)));
        float2 v3 = __half22float2(*(const __half2*)(xw1n + (np[j + 3] << 4) + (fp << 1)));
        a0.x += v0.x; a0.y += v0.y; a1.x += v1.x; a1.y += v1.y;
        a2.x += v2.x; a2.y += v2.y; a3.x += v3.x; a3.y += v3.y;
    }
    for (; j < cc; ++j) {
        float2 v = __half22float2(*(const __half2*)(xw1n + (np[j] << 4) + (fp << 1)));
        a0.x += v.x; a0.y += v.y;
    }
    float2 r = __half22float2(*(const __half2*)(xr1b + (node << 4) + (fp << 1)));
    float rx = fmaxf((a0.x + a1.x + a2.x + a3.x) * inv + r.x, 0.f);
    float ry = fmaxf((a0.y + a1.y + a2.y + a3.y) * inv + r.y, 0.f);
    *(__half2*)(h1 + (node << 4) + (fp << 1)) = __floats2half2_rn(rx, ry);
}

// ---- K6: agg2 = mean_nbrs(h1)  (half2 lanes) ----
__global__ __launch_bounds__(256) void k_agg2(
        const __half* __restrict__ h1,
        const int* __restrict__ deg, const unsigned short* __restrict__ nbr,
        __half* __restrict__ agg2) {
    const int t = blockIdx.x * 256 + threadIdx.x;
    if (t >= N_NODES * 8) return;
    const int node = t >> 3, fp = t & 7;
    int c = deg[node];
    float inv = c > 0 ? 1.f / (float)c : 1.f;
    int cc = c > MAXD ? MAXD : c;
    const unsigned short* np = nbr + (node << 6);
    float2 a0 = {0.f, 0.f}, a1 = {0.f, 0.f}, a2 = {0.f, 0.f}, a3 = {0.f, 0.f};
    int j = 0;
    for (; j + 4 <= cc; j += 4) {
        float2 v0 = __half22float2(*(const __half2*)(h1 + (np[j + 0] << 4) + (fp << 1)));
        float2 v1 = __half22float2(*(const __half2*)(h1 + (np[j + 1] << 4) + (fp << 1)));
        float2 v2 = __half22float2(*(const __half2*)(h1 + (np[j + 2] << 4) + (fp << 1)));
        float2 v3 = __half22float2(*(const __half2*)(h1 + (np[j + 3] << 4) + (fp << 1)));
        a0.x += v0.x; a0.y += v0.y; a1.x += v1.x; a1.y += v1.y;
        a2.x += v2.x; a2.y += v2.y; a3.x += v3.x; a3.y += v3.y;
    }
    for (; j < cc; ++j) {
        float2 v = __half22float2(*(const __half2*)(h1 + (np[j] << 4) + (fp << 1)));
        a0.x += v.x; a0.y += v.y;
    }
    *(__half2*)(agg2 + (node << 4) + (fp << 1)) =
        __floats2half2_rn((a0.x + a1.x + a2.x + a3.x) * inv,
                          (a0.y + a1.y + a2.y + a3.y) * inv);
}

// ---- K7 (k_head, MFMA): SAGE2 + MLP head, transposed D[out][node] ----
// wave = 16 nodes. Weights = A-op (transposed f16 LDS). Activations = B-op.
// C/D: col = lane&15 = node, row = (lane>>4)*4 + r = out-feat.
// B-frag: col = lane&15 = node, k = (lane>>4)*8 + e  -> same node per lane,
// so layer handoff is 8 shfl + cvt_pkrtz per frag (no LDS transpose).
__global__ __launch_bounds__(256) void k_head(
        const __half* __restrict__ h1, const __half* __restrict__ agg2,
        const float* __restrict__ w2n, const float* __restrict__ w2r,
        const float* __restrict__ b2,
        const float* __restrict__ fw1, const float* __restrict__ fb1,
        const float* __restrict__ fw2, const float* __restrict__ fb2,
        const float* __restrict__ fw3, const float* __restrict__ fb3,
        float* __restrict__ out) {
    __shared__ __align__(16) __half s_w2t[32 * 40];     // [out 32][k 32 pad 40]
    __shared__ __align__(16) __half s_fw1t[64 * 40];    // [out 64][k 32 pad 40]
    __shared__ __align__(16) __half s_fw2t[128 * 72];   // [out 128][k 64 pad 72]

    const int tid = threadIdx.x;
    for (int i = tid; i < 1024; i += 256) {
        int o = i & 31, k = i >> 5;
        float v = (k < 16) ? w2n[k * 32 + o] : w2r[(k - 16) * 32 + o];
        s_w2t[o * 40 + k] = __float2half(v);
    }
    for (int i = tid; i < 2048; i += 256) {
        int o = i & 63, k = i >> 6;
        s_fw1t[o * 40 + k] = __float2half(fw1[k * 64 + o]);
    }
    for (int i = tid; i < 8192; i += 256) {
        int o = i & 127, k = i >> 7;
        s_fw2t[o * 72 + k] = __float2half(fw2[k * 128 + o]);
    }
    __syncthreads();

    const int l = tid & 63, li = l & 15, g = l >> 4;
    const int wid = tid >> 6;
    const int node = blockIdx.x * 64 + wid * 16 + li;
    const int nodec = node < N_NODES ? node : N_NODES - 1;
    const int sl0 = li + 32 * (g & 1), sl1 = sl0 + 16;   // shfl sources
    const int tsel = g >> 1;

    // z B-frag: k<16 = agg2[node][0..15], k>=16 = h1[node][0..15] (fp16 direct)
    H8 Bz;
    {
        const __half* zb = (g < 2) ? agg2 : h1;
        Bz.v = *(const uint4*)(zb + (nodec << 4) + ((g & 1) << 3));
    }

    // ---- h2 = relu(z @ W2cat + b2): 2 M-tiles, K=32 ----
    unsigned int p01[2], p23[2];
#pragma unroll
    for (int t = 0; t < 2; ++t) {
        f32x4 c = *(const f32x4*)(b2 + 16 * t + 4 * g);
        H8 A; A.v = *(const uint4*)(s_w2t + (16 * t + li) * 40 + 8 * g);
        c = MM(A, Bz, c);
        p01[t] = pkh(fmaxf(c[0], 0.f), fmaxf(c[1], 0.f));
        p23[t] = pkh(fmaxf(c[2], 0.f), fmaxf(c[3], 0.f));
    }
    H8 Bh2;
    {
        unsigned int a, b;
        a = __shfl((int)p01[0], sl0); b = __shfl((int)p01[1], sl0); Bh2.u[0] = tsel ? b : a;
        a = __shfl((int)p23[0], sl0); b = __shfl((int)p23[1], sl0); Bh2.u[1] = tsel ? b : a;
        a = __shfl((int)p01[0], sl1); b = __shfl((int)p01[1], sl1); Bh2.u[2] = tsel ? b : a;
        a = __shfl((int)p23[0], sl1); b = __shfl((int)p23[1], sl1); Bh2.u[3] = tsel ? b : a;
    }

    // ---- h3 = relu(h2 @ fw1 + fb1): 4 M-tiles, K=32 ----
    unsigned int q01[4], q23[4];
#pragma unroll
    for (int t = 0; t < 4; ++t) {
        f32x4 c = *(const f32x4*)(fb1 + 16 * t + 4 * g);
        H8 A; A.v = *(const uint4*)(s_fw1t + (16 * t + li) * 40 + 8 * g);
        c = MM(A, Bh2, c);
        q01[t] = pkh(fmaxf(c[0], 0.f), fmaxf(c[1], 0.f));
        q23[t] = pkh(fmaxf(c[2], 0.f), fmaxf(c[3], 0.f));
    }
    H8 Bh3[2];
#pragma unroll
    for (int s = 0; s < 2; ++s) {
        unsigned int a, b;
        a = __shfl((int)q01[2 * s], sl0); b = __shfl((int)q01[2 * s + 1], sl0); Bh3[s].u[0] = tsel ? b : a;
        a = __shfl((int)q23[2 * s], sl0); b = __shfl((int)q23[2 * s + 1], sl0); Bh3[s].u[1] = tsel ? b : a;
        a = __shfl((int)q01[2 * s], sl1); b = __shfl((int)q01[2 * s + 1], sl1); Bh3[s].u[2] = tsel ? b : a;
        a = __shfl((int)q23[2 * s], sl1); b = __shfl((int)q23[2 * s + 1], sl1); Bh3[s].u[3] = tsel ? b : a;
    }

    // ---- h4 = relu(h3 @ fw2 + fb2); out = h4 @ fw3: 8 M-tiles, K=64 ----
    float o0 = 0.f, o1 = 0.f;
#pragma unroll
    for (int m = 0; m < 8; ++m) {
        f32x4 c = *(const f32x4*)(fb2 + 16 * m + 4 * g);
        H8 A;
        A.v = *(const uint4*)(s_fw2t + (16 * m + li) * 72 + 8 * g);
        c = MM(A, Bh3[0], c);
        A.v = *(const uint4*)(s_fw2t + (16 * m + li) * 72 + 32 + 8 * g);
        c = MM(A, Bh3[1], c);
        const float4* wp = (const float4*)(fw3 + (16 * m + 4 * g) * 2);
        float4 wA = wp[0], wB = wp[1];
        float r0 = fmaxf(c[0], 0.f), r1 = fmaxf(c[1], 0.f);
        float r2 = fmaxf(c[2], 0.f), r3 = fmaxf(c[3], 0.f);
        o0 += r0 * wA.x + r1 * wA.z + r2 * wB.x + r3 * wB.z;
        o1 += r0 * wA.y + r1 * wA.w + r2 * wB.y + r3 * wB.w;
    }
    o0 += __shfl_xor(o0, 16); o0 += __shfl_xor(o0, 32);
    o1 += __shfl_xor(o1, 16); o1 += __shfl_xor(o1, 32);
    if (g == 0 && node < N_NODES) {
        float2 r; r.x = o0 + fb3[0]; r.y = o1 + fb3[1];
        *(float2*)(out + node * 2) = r;
    }
}

extern "C" void kernel_launch(void* const* d_in, const int* in_sizes, int n_in,
                              void* d_out, int out_size, void* d_ws, size_t ws_size,
                              hipStream_t stream) {
    const float* x   = (const float*)d_in[0];
    const int*   ei  = (const int*)d_in[1];
    const int*   src = ei;
    const int*   dst = ei + N_EDGES;
    const float* w1n = (const float*)d_in[2];
    const float* w1r = (const float*)d_in[3];
    const float* b1  = (const float*)d_in[4];
    const float* w2n = (const float*)d_in[5];
    const float* w2r = (const float*)d_in[6];
    const float* b2  = (const float*)d_in[7];
    const float* fw1 = (const float*)d_in[8];
    const float* fb1 = (const float*)d_in[9];
    const float* fw2 = (const float*)d_in[10];
    const float* fb2 = (const float*)d_in[11];
    const float* fw3 = (const float*)d_in[12];
    const float* fb3 = (const float*)d_in[13];
    float* out = (float*)d_out;

    // workspace layout (~18.6 MB)
    unsigned int*   nbrU        = (unsigned int*)d_ws;              // 50000*32 uints (6.4MB)
    int*            deg         = (int*)(nbrU + N_NODES * 32);      // 50000
    __half*         xw1n        = (__half*)(deg + N_NODES);         // 800000
    __half*         xr1b        = xw1n + N_EDGES;                   // 800000
    __half*         h1          = xr1b + N_EDGES;                   // 800000
    __half*         agg2        = h1 + N_EDGES;                     // 800000
    unsigned int*   staging     = (unsigned int*)(agg2 + N_EDGES);  // 800000 (3.2MB)
    int*            ghist       = (int*)(staging + N_EDGES);        // 50048
    int*            gscan       = ghist + NENT;                     // 50048
    int*            part        = gscan + NENT;                     // 50048
    int*            blockSums   = part + NENT;                      // 196
    int*            bucketStart = blockSums + SCB;                  // 392

    const unsigned short* nbr = (const unsigned short*)nbrU;

    k_lin1<<<(N_NODES + 63) / 64, 256, 0, stream>>>(x, w1n, w1r, b1, xw1n, xr1b);
    k_hist<<<NSCB, 256, 0, stream>>>(dst, ghist);
    k_scanA<<<SCB, 256, 0, stream>>>(ghist, part, blockSums);
    k_scanB<<<1, 256, 0, stream>>>(blockSums);
    k_scanC<<<SCB, 256, 0, stream>>>(part, blockSums, gscan, bucketStart);
    k_scatter<<<NSCB, 256, 0, stream>>>(src, dst, gscan, staging);
    k_build<<<NBUCKET, 256, 0, stream>>>(staging, bucketStart, nbrU, deg);
    k_agg1<<<(N_NODES * 8 + 255) / 256, 256, 0, stream>>>(xw1n, xr1b, deg, nbr, h1);
    k_agg2<<<(N_NODES * 8 + 255) / 256, 256, 0, stream>>>(h1, deg, nbr, agg2);
    k_head<<<(N_NODES + 63) / 64, 256, 0, stream>>>(h1, agg2, w2n, w2r, b2,
                                                    fw1, fb1, fw2, fb2, fw3, fb3, out);
}